// Round 6
// baseline (780.760 us; speedup 1.0000x reference)
//
#include <hip/hip_runtime.h>
#include <math.h>

#define BB 32
#define NN 16384
#define GG 128
#define KK 64
#define HH 128
#define DD 384
#define LN_EPS 1e-5f
#define CAP 1024        // per-wave candidate cap
#define FPSB 4          // fps blocks per batch
#define FPSP (NN / FPSB)

// round-to-nearest sum of 3 squares, matching jnp.sum(x**2, -1) order, no FMA contraction
__device__ __forceinline__ float sq3(float x, float y, float z) {
    return __fadd_rn(__fadd_rn(__fmul_rn(x, x), __fmul_rn(y, y)), __fmul_rn(z, z));
}

// order-preserving uint key of dist2, same formula/rounding as reference
__device__ __forceinline__ unsigned distkey(float px, float py, float pz, float4 c4) {
    float p2 = sq3(px, py, pz);
    float dot = __fadd_rn(__fadd_rn(__fmul_rn(c4.x, px), __fmul_rn(c4.y, py)),
                          __fmul_rn(c4.z, pz));
    float d = __fsub_rn(__fadd_rn(c4.w, p2), __fmul_rn(2.0f, dot));
    unsigned u = __float_as_uint(d);
    return u ^ ((u & 0x80000000u) ? 0xFFFFFFFFu : 0x80000000u);
}

// rank of this lane among set bits below it in a 64-bit wave mask
__device__ __forceinline__ unsigned lanerank(unsigned long long m) {
    unsigned r = __builtin_amdgcn_mbcnt_lo((unsigned)m, 0);
    return __builtin_amdgcn_mbcnt_hi((unsigned)(m >> 32), r);
}

// ---------------- prep: transpose w2 + zero the fps sync area ----------------
__global__ void prep_kernel(const float* __restrict__ w2, float* __restrict__ w2t,
                            unsigned* __restrict__ zeroArea) {
    int i = blockIdx.x * 256 + threadIdx.x;  // 256 blocks x 256 = 65536
    if (i < HH * DD) {
        int f = i >> 7, k = i & 127;
        w2t[i] = w2[k * DD + f];
    }
    int j = i - HH * DD;
    if (j >= 0 && j < 12288) zeroArea[j] = 0u;  // gslot (8192 w) + garr (4096 w)
}

// ---------------- FPS: 4 blocks per batch, points+dist in LDS (no reg-cache gamble) --
__global__ __launch_bounds__(512, 2) void fps_kernel(
    const float* __restrict__ pts, float* __restrict__ cent_out,
    float4* __restrict__ cent_pad, unsigned long long* __restrict__ gslot,
    unsigned* __restrict__ garr) {
    __shared__ float xs[FPSP], ys[FPSP], zs[FPSP], ds[FPSP];  // 64 KB SoA
    __shared__ float wv[8];
    __shared__ int wi[8];
    __shared__ float cen[2][3];
    const int tid = threadIdx.x;
    // 4 blocks of a batch share one XCD (L2 locality + fast same-XCD sync)
    const int x = blockIdx.x & 7, j = blockIdx.x >> 3;
    const int b = x * 4 + (j >> 2), quarter = j & 3;
    const float* pb = pts + (size_t)b * NN * 3;
    const int start = quarter * FPSP;
    const float4* p4s = (const float4*)(pb + start * 3);

    // stage 4096 points into SoA LDS (transpose 3xfloat4 -> x4/y4/z4)
    for (int t = tid; t < FPSP / 4; t += 512) {
        float4 A = p4s[3 * t], Bv = p4s[3 * t + 1], Cv = p4s[3 * t + 2];
        ((float4*)xs)[t] = make_float4(A.x, A.w, Bv.z, Cv.y);
        ((float4*)ys)[t] = make_float4(A.y, Bv.x, Bv.w, Cv.z);
        ((float4*)zs)[t] = make_float4(A.z, Bv.y, Cv.x, Cv.w);
        ((float4*)ds)[t] = make_float4(INFINITY, INFINITY, INFINITY, INFINITY);
    }
    __syncthreads();

    float cx = pb[0], cy = pb[1], cz = pb[2];  // deterministic start at index 0

    for (int it = 0; it < GG; it++) {
        if (quarter == 0 && tid == 0) {
            float* co = cent_out + ((size_t)b * GG + it) * 3;
            co[0] = cx; co[1] = cy; co[2] = cz;
            cent_pad[b * GG + it] = make_float4(cx, cy, cz, sq3(cx, cy, cz));
        }
        if (it == GG - 1) break;  // last argmax unused

        float fv = -INFINITY;
        int fi = 0;
#pragma unroll
        for (int s = 0; s < 8; s++) {
            int n = s * 512 + tid;
            float dx = __fsub_rn(xs[n], cx);
            float dy = __fsub_rn(ys[n], cy);
            float dz = __fsub_rn(zs[n], cz);
            float dd = sq3(dx, dy, dz);
            float od = ds[n];
            float dj = fminf(od, dd);
            if (dd < od) ds[n] = dd;            // predicated write saves LDS BW
            if (dj > fv) { fv = dj; fi = start + n; }  // strict > : lowest idx
        }
#pragma unroll
        for (int off = 32; off >= 1; off >>= 1) {
            float ov = __shfl_down(fv, off);
            int oi = __shfl_down(fi, off);
            if (ov > fv || (ov == fv && oi < fi)) { fv = ov; fi = oi; }
        }
        if ((tid & 63) == 0) { wv[tid >> 6] = fv; wi[tid >> 6] = fi; }
        __syncthreads();
        const int slotI = b * GG + it;
        if (tid == 0) {
            float gv = wv[0];
            int gi = wi[0];
            for (int w = 1; w < 8; w++)
                if (wv[w] > gv || (wv[w] == gv && wi[w] < gi)) { gv = wv[w]; gi = wi[w]; }
            // dist >= 0: float bits order-monotone; ~idx -> lowest index wins max
            unsigned long long packed =
                ((unsigned long long)__float_as_uint(gv) << 32) |
                (unsigned)(0xFFFFFFFFu - (unsigned)gi);
            atomicMax(&gslot[slotI], packed);
            __hip_atomic_fetch_add(&garr[slotI], 1u, __ATOMIC_RELEASE,
                                   __HIP_MEMORY_SCOPE_AGENT);
            while (__hip_atomic_load(&garr[slotI], __ATOMIC_ACQUIRE,
                                     __HIP_MEMORY_SCOPE_AGENT) < (unsigned)FPSB)
                __builtin_amdgcn_s_sleep(1);
            unsigned long long w = __hip_atomic_load(&gslot[slotI], __ATOMIC_RELAXED,
                                                     __HIP_MEMORY_SCOPE_AGENT);
            int idx = (int)(0xFFFFFFFFu - (unsigned)w);
            const float* wp = pb + (size_t)idx * 3;  // L2-hit broadcast read
            cen[it & 1][0] = wp[0]; cen[it & 1][1] = wp[1]; cen[it & 1][2] = wp[2];
        }
        __syncthreads();
        cx = cen[it & 1][0]; cy = cen[it & 1][1]; cz = cen[it & 1][2];
    }
}

// ---------------- group kernel: one WAVE per group, zero barriers ----------------
__global__ __launch_bounds__(256, 4) void group_kernel(
    const float* __restrict__ pts, const float4* __restrict__ cent_pad,
    const float* __restrict__ w1, const float* __restrict__ b1,
    const float* __restrict__ w2t, const float* __restrict__ b2,
    const float* __restrict__ lns, const float* __restrict__ lnb,
    float* __restrict__ tok_out) {
    __shared__ unsigned candKey[4][CAP];        // 16 KB
    __shared__ unsigned short candIdx[4][CAP];  // 8 KB
    __shared__ unsigned short selIdx[4][KK];
    __shared__ float4 localPt[4][KK];
    __shared__ __align__(16) float hbar[4][HH];

    const int tid = threadIdx.x, lane = tid & 63, wid = tid >> 6;
    // 4 waves = 4 consecutive groups of ONE batch (shared point reads via L1/L2);
    // XCD swizzle matches fps so the batch's points are already in this XCD's L2.
    const int x = blockIdx.x & 7, j = blockIdx.x >> 3;
    const int b = x * 4 + (j >> 5);
    const int g = ((j & 31) << 2) + wid;
    const float* p = pts + (size_t)b * NN * 3;
    const float4* p4 = (const float4*)p;
    float4 c4 = cent_pad[b * GG + g];

    // ---- sampling: 512 samples/wave (8/lane, stride 32)
    unsigned sk[8];
#pragma unroll
    for (int s = 0; s < 8; s++) {
        int n = (s * 64 + lane) * 32;
        sk[s] = distkey(p[n * 3], p[n * 3 + 1], p[n * 3 + 2], c4);
    }
    auto sample_kth = [&](int rank) -> unsigned {  // exact kth smallest of 512 samples
        unsigned T = 0u;
        for (int bit = 31; bit >= 0; bit--) {
            unsigned c = T | (1u << bit);
            int cnt = 0;
#pragma unroll
            for (int s = 0; s < 8; s++) cnt += __popcll(__ballot(sk[s] < c));
            if (cnt < rank) T = c;
        }
        return T;
    };
    unsigned* ck = candKey[wid];
    unsigned short* ci = candIdx[wid];
    auto collect = [&](unsigned T) -> int {  // append keys<=T, wave-aggregated, count exact
        int base = 0;
        for (int it2 = 0; it2 < 64; it2++) {
            int q = it2 * 64 + lane;
            float4 A = p4[3 * q], Bv = p4[3 * q + 1], Cv = p4[3 * q + 2];
            unsigned kk[4];
            kk[0] = distkey(A.x, A.y, A.z, c4);
            kk[1] = distkey(A.w, Bv.x, Bv.y, c4);
            kk[2] = distkey(Bv.z, Bv.w, Cv.x, c4);
            kk[3] = distkey(Cv.y, Cv.z, Cv.w, c4);
#pragma unroll
            for (int qq = 0; qq < 4; qq++) {
                bool pred = kk[qq] <= T;
                unsigned long long m = __ballot(pred);
                if (pred) {
                    int pos = base + (int)lanerank(m);
                    if (pos < CAP) { ck[pos] = kk[qq]; ci[pos] = (unsigned short)(4 * q + qq); }
                }
                base += __popcll(m);
            }
        }
        return base;
    };

    unsigned T1 = sample_kth(16);  // E[cnt] ~ 511
    int c1 = collect(T1);
    if (c1 > CAP) { T1 = sample_kth(8); c1 = collect(T1); }  // P ~ 3e-5

    if (c1 >= KK && c1 <= CAP) {
        // ---- exact top-64 SET via 48-step ballot search on (key,idx) pairs
        unsigned long long pr[16];
#pragma unroll
        for (int r = 0; r < 16; r++) {
            int s = r * 64 + lane;
            pr[r] = (s < c1) ? ((((unsigned long long)ck[s]) << 16) | ci[s]) : ~0ull;
        }
        unsigned long long T = 0ull;
        for (int bit = 47; bit >= 0; bit--) {
            unsigned long long c = T | (1ull << bit);
            int cnt = 0;
#pragma unroll
            for (int r = 0; r < 16; r++) cnt += __popcll(__ballot(pr[r] < c));
            if (cnt < KK) T = c;  // ends at exact 64th smallest pair
        }
        int base = 0;
#pragma unroll
        for (int r = 0; r < 16; r++) {
            bool pred = pr[r] <= T;  // exactly 64 pairs (pairs are distinct)
            unsigned long long m = __ballot(pred);
            if (pred) selIdx[wid][base + lanerank(m)] = (unsigned short)(pr[r] & 0xFFFFu);
            base += __popcll(m);
        }
    } else {
        // ---- exact fallback (p ~ 1e-9): 64 rounds of min-extraction with recompute
        unsigned long long last = 0ull;
        for (int r = 0; r < KK; r++) {
            unsigned long long best = ~0ull;
            for (int it2 = 0; it2 < 64; it2++) {
                int q = it2 * 64 + lane;
                float4 A = p4[3 * q], Bv = p4[3 * q + 1], Cv = p4[3 * q + 2];
                unsigned kk[4];
                kk[0] = distkey(A.x, A.y, A.z, c4);
                kk[1] = distkey(A.w, Bv.x, Bv.y, c4);
                kk[2] = distkey(Bv.z, Bv.w, Cv.x, c4);
                kk[3] = distkey(Cv.y, Cv.z, Cv.w, c4);
#pragma unroll
                for (int qq = 0; qq < 4; qq++) {
                    unsigned long long pp =
                        (((unsigned long long)kk[qq]) << 16) | (unsigned)(4 * q + qq);
                    if ((r == 0 || pp > last) && pp < best) best = pp;
                }
            }
#pragma unroll
            for (int off = 32; off >= 1; off >>= 1) {
                unsigned long long o = __shfl_xor(best, off);
                if (o < best) best = o;
            }
            selIdx[wid][r] = (unsigned short)(best & 0xFFFFu);
            last = best;
        }
    }

    // ---- gather local coords (wave-internal, no barrier needed)
    {
        int n = selIdx[wid][lane];
        localPt[wid][lane] =
            make_float4(p[n * 3] - c4.x, p[n * 3 + 1] - c4.y, p[n * 3 + 2] - c4.z, 0.f);
    }
    // ---- layer1 + exact GELU + mean over 64 neighbors (2 features per lane)
    {
        float wa0 = w1[lane], wb0 = w1[HH + lane], wc0 = w1[2 * HH + lane], bb0 = b1[lane];
        float wa1 = w1[64 + lane], wb1 = w1[HH + 64 + lane], wc1 = w1[2 * HH + 64 + lane],
              bb1 = b1[64 + lane];
        float s0 = 0.f, s1 = 0.f;
        for (int k = 0; k < KK; k++) {
            float4 lp = localPt[wid][k];  // broadcast LDS read
            float a0 = lp.x * wa0 + lp.y * wb0 + lp.z * wc0 + bb0;
            float a1 = lp.x * wa1 + lp.y * wb1 + lp.z * wc1 + bb1;
            s0 += 0.5f * a0 * (1.0f + erff(a0 * 0.70710678118654752440f));
            s1 += 0.5f * a1 * (1.0f + erff(a1 * 0.70710678118654752440f));
        }
        hbar[wid][lane] = s0 * (1.0f / 64.0f);
        hbar[wid][64 + lane] = s1 * (1.0f / 64.0f);
    }
    // ---- layer2 (mean commutes with linear): 6 features per lane, then LN
    {
        const int f0 = lane * 6;
        float acc0 = b2[f0], acc1 = b2[f0 + 1], acc2 = b2[f0 + 2];
        float acc3 = b2[f0 + 3], acc4 = b2[f0 + 4], acc5 = b2[f0 + 5];
        const float4* hb = (const float4*)hbar[wid];
        for (int q = 0; q < HH / 4; q++) {
            float4 h4 = hb[q];  // broadcast
            const float* w0 = w2t + (size_t)f0 * HH + 4 * q;
            float4 a = *(const float4*)(w0);
            float4 bq = *(const float4*)(w0 + HH);
            float4 cq = *(const float4*)(w0 + 2 * HH);
            float4 dq = *(const float4*)(w0 + 3 * HH);
            float4 eq = *(const float4*)(w0 + 4 * HH);
            float4 fq = *(const float4*)(w0 + 5 * HH);
            acc0 += h4.x * a.x + h4.y * a.y + h4.z * a.z + h4.w * a.w;
            acc1 += h4.x * bq.x + h4.y * bq.y + h4.z * bq.z + h4.w * bq.w;
            acc2 += h4.x * cq.x + h4.y * cq.y + h4.z * cq.z + h4.w * cq.w;
            acc3 += h4.x * dq.x + h4.y * dq.y + h4.z * dq.z + h4.w * dq.w;
            acc4 += h4.x * eq.x + h4.y * eq.y + h4.z * eq.z + h4.w * eq.w;
            acc5 += h4.x * fq.x + h4.y * fq.y + h4.z * fq.z + h4.w * fq.w;
        }
        float s1v = acc0 + acc1 + acc2 + acc3 + acc4 + acc5;
        float s2v = acc0 * acc0 + acc1 * acc1 + acc2 * acc2 + acc3 * acc3 +
                    acc4 * acc4 + acc5 * acc5;
#pragma unroll
        for (int off = 32; off >= 1; off >>= 1) {
            s1v += __shfl_xor(s1v, off);
            s2v += __shfl_xor(s2v, off);
        }
        float mu = s1v / (float)DD;
        float var = s2v / (float)DD - mu * mu;
        float rstd = rsqrtf(var + LN_EPS);
        float* outp = tok_out + ((size_t)b * GG + g) * DD + f0;
        outp[0] = (acc0 - mu) * rstd * lns[f0] + lnb[f0];
        outp[1] = (acc1 - mu) * rstd * lns[f0 + 1] + lnb[f0 + 1];
        outp[2] = (acc2 - mu) * rstd * lns[f0 + 2] + lnb[f0 + 2];
        outp[3] = (acc3 - mu) * rstd * lns[f0 + 3] + lnb[f0 + 3];
        outp[4] = (acc4 - mu) * rstd * lns[f0 + 4] + lnb[f0 + 4];
        outp[5] = (acc5 - mu) * rstd * lns[f0 + 5] + lnb[f0 + 5];
    }
}

extern "C" void kernel_launch(void* const* d_in, const int* in_sizes, int n_in,
                              void* d_out, int out_size, void* d_ws, size_t ws_size,
                              hipStream_t stream) {
    const float* pts = (const float*)d_in[0];
    const float* w1 = (const float*)d_in[1];
    const float* b1 = (const float*)d_in[2];
    const float* w2 = (const float*)d_in[3];
    const float* b2 = (const float*)d_in[4];
    const float* lns = (const float*)d_in[5];
    const float* lnb = (const float*)d_in[6];
    float* out = (float*)d_out;

    // ws layout: cent_pad 64KB | w2t 192KB | gslot 32KB | garr 16KB  (total 304KB)
    float4* cent_pad = (float4*)d_ws;
    float* w2t = (float*)((char*)d_ws + 65536);
    unsigned long long* gslot = (unsigned long long*)((char*)d_ws + 262144);
    unsigned* garr = (unsigned*)((char*)d_ws + 294912);

    prep_kernel<<<256, 256, 0, stream>>>(w2, w2t, (unsigned*)gslot);
    fps_kernel<<<128, 512, 0, stream>>>(pts, out, cent_pad, gslot, garr);
    group_kernel<<<1024, 256, 0, stream>>>(pts, cent_pad, w1, b1, w2t, b2, lns, lnb,
                                           out + BB * GG * 3);
}

// Round 7
// 591.298 us; speedup vs baseline: 1.3204x; 1.3204x over previous
//
#include <hip/hip_runtime.h>
#include <math.h>

#define BB 32
#define NN 16384
#define GG 128
#define KK 64
#define HH 128
#define DD 384
#define LN_EPS 1e-5f
#define CAP 1024        // per-wave candidate cap

// round-to-nearest sum of 3 squares, matching jnp.sum(x**2, -1) order, no FMA contraction
__device__ __forceinline__ float sq3(float x, float y, float z) {
    return __fadd_rn(__fadd_rn(__fmul_rn(x, x), __fmul_rn(y, y)), __fmul_rn(z, z));
}

// order-preserving uint key of dist2, same formula/rounding as reference
__device__ __forceinline__ unsigned distkey(float px, float py, float pz, float4 c4) {
    float p2 = sq3(px, py, pz);
    float dot = __fadd_rn(__fadd_rn(__fmul_rn(c4.x, px), __fmul_rn(c4.y, py)),
                          __fmul_rn(c4.z, pz));
    float d = __fsub_rn(__fadd_rn(c4.w, p2), __fmul_rn(2.0f, dot));
    unsigned u = __float_as_uint(d);
    return u ^ ((u & 0x80000000u) ? 0xFFFFFFFFu : 0x80000000u);
}

// rank of this lane among set bits below it in a 64-bit wave mask
__device__ __forceinline__ unsigned lanerank(unsigned long long m) {
    unsigned r = __builtin_amdgcn_mbcnt_lo((unsigned)m, 0);
    return __builtin_amdgcn_mbcnt_hi((unsigned)(m >> 32), r);
}

// ---------------- prep: transpose w2 [128,384] -> w2t [384,128] ----------------
__global__ void prep_kernel(const float* __restrict__ w2, float* __restrict__ w2t) {
    int i = blockIdx.x * 256 + threadIdx.x;
    if (i < HH * DD) {
        int f = i >> 7, k = i & 127;
        w2t[i] = w2[k * DD + f];
    }
}

// ---------------- FPS: ONE block per batch (no cross-block sync - R6 showed that
// costs 3.6us/iter), 1024 threads (4 waves/SIMD latency hiding), dist in LDS
// (architectural residency - the register allocator demoted every reg-cache attempt
// in R3/R4/R5), xyz streamed from L2 (~0.2us/iter BW, latency hidden by 12
// independent dwordx4 loads/thread). ----------------
__global__ __launch_bounds__(1024, 4) void fps_kernel(const float* __restrict__ pts,
                                                      float* __restrict__ cent_out,
                                                      float4* __restrict__ cent_pad) {
    __shared__ float4 ds4[NN / 4];           // 64 KB quad-packed dist
    __shared__ unsigned long long slot[GG];  // per-iteration argmax slot, pre-zeroed
    const int b = blockIdx.x;
    const int tid = threadIdx.x;
    const float* p = pts + (size_t)b * NN * 3;
    const float4* p4 = (const float4*)p;

    for (int i = tid; i < NN / 4; i += 1024)
        ds4[i] = make_float4(INFINITY, INFINITY, INFINITY, INFINITY);
    for (int i = tid; i < GG; i += 1024) slot[i] = 0ull;
    __syncthreads();

    float cx = p[0], cy = p[1], cz = p[2];  // deterministic start at index 0

    for (int it = 0; it < GG; it++) {
        if (tid == 0) {
            float* co = cent_out + ((size_t)b * GG + it) * 3;
            co[0] = cx; co[1] = cy; co[2] = cz;
            cent_pad[b * GG + it] = make_float4(cx, cy, cz, sq3(cx, cy, cz));
        }
        if (it == GG - 1) break;  // last argmax unused

        // 4 component chains (strict > keeps lowest q); idx = 4q+c
        float bv0 = -INFINITY, bv1 = -INFINITY, bv2 = -INFINITY, bv3 = -INFINITY;
        int bq0 = 0, bq1 = 0, bq2 = 0, bq3 = 0;
#pragma unroll
        for (int j = 0; j < 4; j++) {
            int q = tid + j * 1024;
            float4 A = p4[3 * q], B = p4[3 * q + 1], C = p4[3 * q + 2];
            float4 dv = ds4[q];
            float d0 = sq3(__fsub_rn(A.x, cx), __fsub_rn(A.y, cy), __fsub_rn(A.z, cz));
            float d1 = sq3(__fsub_rn(A.w, cx), __fsub_rn(B.x, cy), __fsub_rn(B.y, cz));
            float d2 = sq3(__fsub_rn(B.z, cx), __fsub_rn(B.w, cy), __fsub_rn(C.x, cz));
            float d3 = sq3(__fsub_rn(C.y, cx), __fsub_rn(C.z, cy), __fsub_rn(C.w, cz));
            float n0 = fminf(dv.x, d0), n1 = fminf(dv.y, d1);
            float n2 = fminf(dv.z, d2), n3 = fminf(dv.w, d3);
            bool ch = (d0 < dv.x) | (d1 < dv.y) | (d2 < dv.z) | (d3 < dv.w);
            if (ch) ds4[q] = make_float4(n0, n1, n2, n3);
            if (n0 > bv0) { bv0 = n0; bq0 = q; }
            if (n1 > bv1) { bv1 = n1; bq1 = q; }
            if (n2 > bv2) { bv2 = n2; bq2 = q; }
            if (n3 > bv3) { bv3 = n3; bq3 = q; }
        }
        float fv = bv0; int fi = 4 * bq0;
        {
            int i1 = 4 * bq1 + 1, i2 = 4 * bq2 + 2, i3 = 4 * bq3 + 3;
            if (bv1 > fv || (bv1 == fv && i1 < fi)) { fv = bv1; fi = i1; }
            if (bv2 > fv || (bv2 == fv && i2 < fi)) { fv = bv2; fi = i2; }
            if (bv3 > fv || (bv3 == fv && i3 < fi)) { fv = bv3; fi = i3; }
        }
#pragma unroll
        for (int off = 32; off >= 1; off >>= 1) {
            float ov = __shfl_down(fv, off);
            int oi = __shfl_down(fi, off);
            if (ov > fv || (ov == fv && oi < fi)) { fv = ov; fi = oi; }
        }
        // dist >= 0: float bits order-monotone; ~idx -> lowest index wins at equal value
        if ((tid & 63) == 0) {
            unsigned long long packed =
                ((unsigned long long)__float_as_uint(fv) << 32) |
                (unsigned)(0xFFFFFFFFu - (unsigned)fi);
            atomicMax(&slot[it], packed);
        }
        __syncthreads();  // only barrier per iteration
        unsigned long long w = slot[it];
        int idx = (int)(0xFFFFFFFFu - (unsigned)w);
        const float* wp = p + (size_t)idx * 3;  // broadcast same-address load, L1/L2-hit
        cx = wp[0]; cy = wp[1]; cz = wp[2];
    }
}

// ---------------- group kernel: one WAVE per group ----------------
__global__ __launch_bounds__(256, 4) void group_kernel(
    const float* __restrict__ pts, const float4* __restrict__ cent_pad,
    const float* __restrict__ w1, const float* __restrict__ b1,
    const float* __restrict__ w2t, const float* __restrict__ b2,
    const float* __restrict__ lns, const float* __restrict__ lnb,
    float* __restrict__ tok_out) {
    __shared__ unsigned candKey[4][CAP];        // 16 KB
    __shared__ unsigned short candIdx[4][CAP];  // 8 KB
    __shared__ unsigned short tieIdx[4][128];   // 1 KB
    __shared__ unsigned short selIdx[4][KK];
    __shared__ float4 localPt[4][KK];
    __shared__ __align__(16) float hbar[4][HH];

    const int tid = threadIdx.x, lane = tid & 63, wid = tid >> 6;
    // 4 waves = 4 groups of ONE batch (shared point stream via L1/L2)
    const int x = blockIdx.x & 7, j = blockIdx.x >> 3;
    const int b = x * 4 + (j >> 5);
    const int g = ((j & 31) << 2) + wid;
    const float* p = pts + (size_t)b * NN * 3;
    const float4* p4 = (const float4*)p;
    float4 c4 = cent_pad[b * GG + g];

    // ---- sampling: 512 samples/wave (8/lane, stride 32 points)
    unsigned sk[8];
#pragma unroll
    for (int s = 0; s < 8; s++) {
        int n = (s * 64 + lane) * 32;
        sk[s] = distkey(p[n * 3], p[n * 3 + 1], p[n * 3 + 2], c4);
    }
    auto sample_kth = [&](int rank) -> unsigned {  // exact kth(1-idx) smallest of 512
        unsigned T = 0u;
        for (int bit = 31; bit >= 0; bit--) {
            unsigned c = T | (1u << bit);
            int cnt = 0;
#pragma unroll
            for (int s = 0; s < 8; s++) cnt += __popcll(__ballot(sk[s] < c));
            if (cnt < rank) T = c;
        }
        return T;
    };
    unsigned* ck = candKey[wid];
    unsigned short* ci = candIdx[wid];

    // main collect: unroll x2 with hoisted loads; barrier every 8 logical iters to
    // keep the block's 4 waves streaming the same 24KB tile (L1 reuse). ALL waves
    // execute this exactly once -> barriers are uniform.
    unsigned T1 = sample_kth(16);  // E[cnt] ~ 511
    int cnt;
    {
        int base = 0;
        for (int u = 0; u < 32; u++) {
            int qa = u * 128 + lane, qb = qa + 64;
            float4 Aa = p4[3 * qa], Ba = p4[3 * qa + 1], Ca = p4[3 * qa + 2];
            float4 Ab = p4[3 * qb], Bb2 = p4[3 * qb + 1], Cb = p4[3 * qb + 2];
#pragma unroll
            for (int t = 0; t < 2; t++) {
                int q = t ? qb : qa;
                float4 A = t ? Ab : Aa, Bv = t ? Bb2 : Ba, Cv = t ? Cb : Ca;
                unsigned kk[4];
                kk[0] = distkey(A.x, A.y, A.z, c4);
                kk[1] = distkey(A.w, Bv.x, Bv.y, c4);
                kk[2] = distkey(Bv.z, Bv.w, Cv.x, c4);
                kk[3] = distkey(Cv.y, Cv.z, Cv.w, c4);
#pragma unroll
                for (int qq = 0; qq < 4; qq++) {
                    bool pred = kk[qq] <= T1;
                    unsigned long long m = __ballot(pred);
                    if (pred) {
                        int pos = base + (int)lanerank(m);
                        if (pos < CAP) {
                            ck[pos] = kk[qq];
                            ci[pos] = (unsigned short)(4 * q + qq);
                        }
                    }
                    base += __popcll(m);
                }
            }
            if ((u & 3) == 3) __syncthreads();
        }
        cnt = base;
    }

    // barrier-free re-collect for the rare overflow (P ~ 6e-4/wave)
    auto collect_ns = [&](unsigned T) -> int {
        int base = 0;
        for (int it2 = 0; it2 < 64; it2++) {
            int q = it2 * 64 + lane;
            float4 A = p4[3 * q], Bv = p4[3 * q + 1], Cv = p4[3 * q + 2];
            unsigned kk[4];
            kk[0] = distkey(A.x, A.y, A.z, c4);
            kk[1] = distkey(A.w, Bv.x, Bv.y, c4);
            kk[2] = distkey(Bv.z, Bv.w, Cv.x, c4);
            kk[3] = distkey(Cv.y, Cv.z, Cv.w, c4);
#pragma unroll
            for (int qq = 0; qq < 4; qq++) {
                bool pred = kk[qq] <= T;
                unsigned long long m = __ballot(pred);
                if (pred) {
                    int pos = base + (int)lanerank(m);
                    if (pos < CAP) {
                        ck[pos] = kk[qq];
                        ci[pos] = (unsigned short)(4 * q + qq);
                    }
                }
                base += __popcll(m);
            }
        }
        return base;
    };
    if (cnt > CAP) cnt = collect_ns(sample_kth(8));  // E[cnt] ~ 255

    bool fallback = (cnt < KK || cnt > CAP);
    if (!fallback) {
        // ---- exact: 32-step ballot search for the 64th smallest KEY
        unsigned k8[16];
#pragma unroll
        for (int r = 0; r < 16; r++) {
            int s = r * 64 + lane;
            k8[r] = (s < cnt) ? ck[s] : 0xFFFFFFFFu;  // sentinel > any finite key
        }
        unsigned T = 0u;
        for (int bit = 31; bit >= 0; bit--) {
            unsigned c = T | (1u << bit);
            int cl = 0;
#pragma unroll
            for (int r = 0; r < 16; r++) cl += __popcll(__ballot(k8[r] < c));
            if (cl < KK) T = c;  // final T = 64th smallest key
        }
        int cless = 0;
#pragma unroll
        for (int r = 0; r < 16; r++) cless += __popcll(__ballot(k8[r] < T));
        int need = KK - cless;
        // keys < T: selected unconditionally (set semantics, order irrelevant)
        int base2 = 0;
#pragma unroll
        for (int r = 0; r < 16; r++) {
            bool pr = k8[r] < T;
            unsigned long long m = __ballot(pr);
            if (pr) selIdx[wid][base2 + lanerank(m)] = ci[r * 64 + lane];
            base2 += __popcll(m);
        }
        // ties at T: lowest `need` indices win (explicit index ranking)
        int tb = 0;
#pragma unroll
        for (int r = 0; r < 16; r++) {
            bool pr = (r * 64 + lane < cnt) && (k8[r] == T);
            unsigned long long m = __ballot(pr);
            if (pr) {
                int pos = tb + (int)lanerank(m);
                if (pos < 128) tieIdx[wid][pos] = ci[r * 64 + lane];
            }
            tb += __popcll(m);
        }
        if (tb > 128) {
            fallback = true;
        } else {
#pragma unroll
            for (int rr = 0; rr < 2; rr++) {
                int t = lane + rr * 64;
                if (t < tb) {
                    unsigned short my = tieIdx[wid][t];
                    int rank = 0;
                    for (int j2 = 0; j2 < tb; j2++) rank += (tieIdx[wid][j2] < my);
                    if (rank < need) selIdx[wid][cless + rank] = my;
                }
            }
        }
    }
    if (fallback) {
        // exact 64-round min-extraction with recompute (p ~ 0; barrier-free)
        unsigned long long last = 0ull;
        for (int r = 0; r < KK; r++) {
            unsigned long long best = ~0ull;
            for (int it2 = 0; it2 < 64; it2++) {
                int q = it2 * 64 + lane;
                float4 A = p4[3 * q], Bv = p4[3 * q + 1], Cv = p4[3 * q + 2];
                unsigned kk[4];
                kk[0] = distkey(A.x, A.y, A.z, c4);
                kk[1] = distkey(A.w, Bv.x, Bv.y, c4);
                kk[2] = distkey(Bv.z, Bv.w, Cv.x, c4);
                kk[3] = distkey(Cv.y, Cv.z, Cv.w, c4);
#pragma unroll
                for (int qq = 0; qq < 4; qq++) {
                    unsigned long long pp =
                        (((unsigned long long)kk[qq]) << 16) | (unsigned)(4 * q + qq);
                    if ((r == 0 || pp > last) && pp < best) best = pp;
                }
            }
#pragma unroll
            for (int off = 32; off >= 1; off >>= 1) {
                unsigned long long o = __shfl_xor(best, off);
                if (o < best) best = o;
            }
            selIdx[wid][r] = (unsigned short)(best & 0xFFFFu);
            last = best;
        }
    }
    __syncthreads();  // converge all 4 waves (aligns w2t streaming in the epilogue)

    // ---- gather local coords (wave-internal)
    {
        int n = selIdx[wid][lane];
        localPt[wid][lane] =
            make_float4(p[n * 3] - c4.x, p[n * 3 + 1] - c4.y, p[n * 3 + 2] - c4.z, 0.f);
    }
    // ---- layer1 + exact GELU + mean over 64 neighbors (2 features per lane)
    {
        float wa0 = w1[lane], wb0 = w1[HH + lane], wc0 = w1[2 * HH + lane], bb0 = b1[lane];
        float wa1 = w1[64 + lane], wb1 = w1[HH + 64 + lane], wc1 = w1[2 * HH + 64 + lane],
              bb1 = b1[64 + lane];
        float s0 = 0.f, s1 = 0.f;
        for (int k = 0; k < KK; k++) {
            float4 lp = localPt[wid][k];  // broadcast LDS read
            float a0 = lp.x * wa0 + lp.y * wb0 + lp.z * wc0 + bb0;
            float a1 = lp.x * wa1 + lp.y * wb1 + lp.z * wc1 + bb1;
            s0 += 0.5f * a0 * (1.0f + erff(a0 * 0.70710678118654752440f));
            s1 += 0.5f * a1 * (1.0f + erff(a1 * 0.70710678118654752440f));
        }
        hbar[wid][lane] = s0 * (1.0f / 64.0f);
        hbar[wid][64 + lane] = s1 * (1.0f / 64.0f);
    }
    // ---- layer2 (mean commutes with linear): 6 features per lane, then LN
    {
        const int f0 = lane * 6;
        float acc0 = b2[f0], acc1 = b2[f0 + 1], acc2 = b2[f0 + 2];
        float acc3 = b2[f0 + 3], acc4 = b2[f0 + 4], acc5 = b2[f0 + 5];
        const float4* hb = (const float4*)hbar[wid];
        for (int q = 0; q < HH / 4; q++) {
            float4 h4 = hb[q];  // broadcast
            const float* w0 = w2t + (size_t)f0 * HH + 4 * q;
            float4 a = *(const float4*)(w0);
            float4 bq = *(const float4*)(w0 + HH);
            float4 cq = *(const float4*)(w0 + 2 * HH);
            float4 dq = *(const float4*)(w0 + 3 * HH);
            float4 eq = *(const float4*)(w0 + 4 * HH);
            float4 fq = *(const float4*)(w0 + 5 * HH);
            acc0 += h4.x * a.x + h4.y * a.y + h4.z * a.z + h4.w * a.w;
            acc1 += h4.x * bq.x + h4.y * bq.y + h4.z * bq.z + h4.w * bq.w;
            acc2 += h4.x * cq.x + h4.y * cq.y + h4.z * cq.z + h4.w * cq.w;
            acc3 += h4.x * dq.x + h4.y * dq.y + h4.z * dq.z + h4.w * dq.w;
            acc4 += h4.x * eq.x + h4.y * eq.y + h4.z * eq.z + h4.w * eq.w;
            acc5 += h4.x * fq.x + h4.y * fq.y + h4.z * fq.z + h4.w * fq.w;
        }
        float s1v = acc0 + acc1 + acc2 + acc3 + acc4 + acc5;
        float s2v = acc0 * acc0 + acc1 * acc1 + acc2 * acc2 + acc3 * acc3 +
                    acc4 * acc4 + acc5 * acc5;
#pragma unroll
        for (int off = 32; off >= 1; off >>= 1) {
            s1v += __shfl_xor(s1v, off);
            s2v += __shfl_xor(s2v, off);
        }
        float mu = s1v / (float)DD;
        float var = s2v / (float)DD - mu * mu;
        float rstd = rsqrtf(var + LN_EPS);
        float* outp = tok_out + ((size_t)b * GG + g) * DD + f0;
        outp[0] = (acc0 - mu) * rstd * lns[f0] + lnb[f0];
        outp[1] = (acc1 - mu) * rstd * lns[f0 + 1] + lnb[f0 + 1];
        outp[2] = (acc2 - mu) * rstd * lns[f0 + 2] + lnb[f0 + 2];
        outp[3] = (acc3 - mu) * rstd * lns[f0 + 3] + lnb[f0 + 3];
        outp[4] = (acc4 - mu) * rstd * lns[f0 + 4] + lnb[f0 + 4];
        outp[5] = (acc5 - mu) * rstd * lns[f0 + 5] + lnb[f0 + 5];
    }
}

extern "C" void kernel_launch(void* const* d_in, const int* in_sizes, int n_in,
                              void* d_out, int out_size, void* d_ws, size_t ws_size,
                              hipStream_t stream) {
    const float* pts = (const float*)d_in[0];
    const float* w1 = (const float*)d_in[1];
    const float* b1 = (const float*)d_in[2];
    const float* w2 = (const float*)d_in[3];
    const float* b2 = (const float*)d_in[4];
    const float* lns = (const float*)d_in[5];
    const float* lnb = (const float*)d_in[6];
    float* out = (float*)d_out;

    // ws layout: cent_pad 64KB | w2t 192KB
    float4* cent_pad = (float4*)d_ws;
    float* w2t = (float*)((char*)d_ws + 65536);

    prep_kernel<<<192, 256, 0, stream>>>(w2, w2t);
    fps_kernel<<<BB, 1024, 0, stream>>>(pts, out, cent_pad);
    group_kernel<<<1024, 256, 0, stream>>>(pts, cent_pad, w1, b1, w2t, b2, lns, lnb,
                                           out + BB * GG * 3);
}